// Round 8
// baseline (255.570 us; speedup 1.0000x reference)
//
#include <hip/hip_runtime.h>

typedef __bf16 bf16x8 __attribute__((ext_vector_type(8)));
typedef float f32x16 __attribute__((ext_vector_type(16)));

// global -> LDS direct copy: per-lane 16 B from gsrc(+lane*16 included by caller),
// written at wave-uniform ldst + lane*16 (HW rule, m104). size must be literal 16.
#define GLOAD_LDS16(gsrc, ldst)                                                   \
  __builtin_amdgcn_global_load_lds(                                               \
      (const __attribute__((address_space(1))) void*)(gsrc),                      \
      (__attribute__((address_space(3))) void*)(ldst), 16, 0, 0)

// ---------------------------------------------------------------------------
// Pack W (512x512 f32, row-major W[k][n]) into bf16 MFMA-fragment order:
//   P[((c*32 + kb)*64 + l)*8 + e] = W[kb*16 + (l>>5)*8 + e][c*32 + (l&31)]
// ---------------------------------------------------------------------------
__global__ __launch_bounds__(256) void prep_pack(const float* __restrict__ Wcb,
                                                 const float* __restrict__ Wcc,
                                                 __bf16* __restrict__ Pb,
                                                 __bf16* __restrict__ Pc) {
  int idx = blockIdx.x * 256 + threadIdx.x;          // 0 .. 524287
  const float* src = (idx < 262144) ? Wcb : Wcc;
  __bf16* dst = (idx < 262144) ? Pb : Pc;
  int t = idx & 262143;
  int e = t & 7, l = (t >> 3) & 63, kb = (t >> 9) & 31, c = t >> 14;
  int k = kb * 16 + ((l >> 5) << 3) + e;
  int n = (c << 5) + (l & 31);
  dst[t] = (__bf16)src[k * 512 + n];                 // stores coalesced
}

// ---------------------------------------------------------------------------
// Small fp32 GEMM for the node MLP: C[1024,N] = act(A[1024,K] @ W[K,N] + bias)
// ---------------------------------------------------------------------------
__global__ __launch_bounds__(256) void gemm_f32(const float* __restrict__ A,
                                                const float* __restrict__ W,
                                                const float* __restrict__ bias,
                                                float* __restrict__ C,
                                                int K, int N, int do_relu) {
  __shared__ float As[16][68];
  __shared__ float Ws[16][32];
  int bm = blockIdx.x * 64, bn = blockIdx.y * 32;
  int tid = threadIdx.x;
  int tx = tid & 15, ty = tid >> 4;
  float acc[4][2] = {};
  for (int k0 = 0; k0 < K; k0 += 16) {
#pragma unroll
    for (int ii = 0; ii < 4; ii++) {
      int e = ii * 256 + tid; int r = e >> 4, c = e & 15;
      As[c][r] = A[(bm + r) * K + k0 + c];
    }
#pragma unroll
    for (int ii = 0; ii < 2; ii++) {
      int e = ii * 256 + tid; int kr = e >> 5, c = e & 31;
      Ws[kr][c] = W[(k0 + kr) * N + bn + c];
    }
    __syncthreads();
#pragma unroll
    for (int kk = 0; kk < 16; kk++) {
      float4 a = *(const float4*)&As[kk][ty * 4];
      float2 w = *(const float2*)&Ws[kk][tx * 2];
      acc[0][0] += a.x * w.x; acc[0][1] += a.x * w.y;
      acc[1][0] += a.y * w.x; acc[1][1] += a.y * w.y;
      acc[2][0] += a.z * w.x; acc[2][1] += a.z * w.y;
      acc[3][0] += a.w * w.x; acc[3][1] += a.w * w.y;
    }
    __syncthreads();
  }
#pragma unroll
  for (int mi = 0; mi < 4; mi++)
#pragma unroll
    for (int ni = 0; ni < 2; ni++) {
      int n = bn + tx * 2 + ni;
      float vv = acc[mi][ni] + (bias ? bias[n] : 0.f);
      if (do_relu) vv = fmaxf(vv, 0.f);
      C[(bm + ty * 4 + mi) * N + n] = vv;
    }
}

// ---------------------------------------------------------------------------
// Fused u/v kernel: u = f @ Wca[0:512,:], v = f @ Wca[512:1024,:]
// ---------------------------------------------------------------------------
__global__ __launch_bounds__(256) void gemm_uv(const float* __restrict__ A,
                                               const float* __restrict__ Wca,
                                               float* __restrict__ u,
                                               float* __restrict__ v) {
  __shared__ float As[16][68];
  __shared__ float Ws[16][32];
  int half = blockIdx.y >> 4;
  const float* W = Wca + half * 512 * 512;
  float* C = half ? v : u;
  int bm = blockIdx.x * 64, bn = (blockIdx.y & 15) * 32;
  int tid = threadIdx.x;
  int tx = tid & 15, ty = tid >> 4;
  float acc[4][2] = {};
  for (int k0 = 0; k0 < 512; k0 += 16) {
#pragma unroll
    for (int ii = 0; ii < 4; ii++) {
      int e = ii * 256 + tid; int r = e >> 4, c = e & 15;
      As[c][r] = A[(bm + r) * 512 + k0 + c];
    }
#pragma unroll
    for (int ii = 0; ii < 2; ii++) {
      int e = ii * 256 + tid; int kr = e >> 5, c = e & 31;
      Ws[kr][c] = W[(k0 + kr) * 512 + bn + c];
    }
    __syncthreads();
#pragma unroll
    for (int kk = 0; kk < 16; kk++) {
      float4 a = *(const float4*)&As[kk][ty * 4];
      float2 w = *(const float2*)&Ws[kk][tx * 2];
      acc[0][0] += a.x * w.x; acc[0][1] += a.x * w.y;
      acc[1][0] += a.y * w.x; acc[1][1] += a.y * w.y;
      acc[2][0] += a.z * w.x; acc[2][1] += a.z * w.y;
      acc[3][0] += a.w * w.x; acc[3][1] += a.w * w.y;
    }
    __syncthreads();
  }
#pragma unroll
  for (int mi = 0; mi < 4; mi++)
#pragma unroll
    for (int ni = 0; ni < 2; ni++)
      C[(bm + ty * 4 + mi) * 512 + bn + tx * 2 + ni] = acc[mi][ni];
}

// ---------------------------------------------------------------------------
// Fused edge kernel — r7 dataflow with LDS-staged B (T3 minimum 2-phase):
// per kb-step the WG stages the NEXT step's 16 KB of packed B into a
// double-buffer via global_load_lds (2 instr/wave), computes the current
// step from LDS, then one __syncthreads (implicit vmcnt(0) drain, loads had
// the whole step to land). MFMAs wait only on lgkmcnt for short ds_reads.
// LDS 160 KB: h tiles 2x64 KB @0/@65536, B dbuf 2x16 KB @131072.
// B chunk cb (col-block) lives at Bst + sel*16384 + cb*1024 + lane*16,
// staged by wave cb>>1 — per-lane values identical to r7's direct loads.
// ---------------------------------------------------------------------------
__global__ __launch_bounds__(512, 2) void edge_kernel(
    const float* __restrict__ u, const float* __restrict__ v,
    const bf16x8* __restrict__ Pb, const bf16x8* __restrict__ Pc,
    const float* __restrict__ bca, const float* __restrict__ bcb,
    const float* __restrict__ bcc, const float* __restrict__ Wo,
    const float* __restrict__ bo, float* __restrict__ out) {
  __shared__ __align__(16) char h_raw[163840];
  char* Bst = h_raw + 131072;

  int wg = blockIdx.x;                 // b*128 + i
  int i = wg & 127, b = wg >> 7;
  int tid = threadIdx.x, lane = tid & 63, w = tid >> 6;

  int mrow = (w & 1) * 32;
  int n0 = (w >> 1) * 128;
  int cg4 = (w >> 1) * 4;              // first col-block this wave consumes
  int arow = mrow + (lane & 31);
  int sA = (arow & 15) << 4;
  int klo = (lane >> 5) * 8;
  int cb0 = 2 * w;                     // col-block chunks this wave stages

#define STAGE_B(P, kb, sel)                                                       \
  {                                                                               \
    const char* _g0 = (const char*)((P) + (cb0 * 32 + (kb)) * 64) + lane * 16;    \
    const char* _g1 = (const char*)((P) + ((cb0 + 1) * 32 + (kb)) * 64) + lane * 16; \
    GLOAD_LDS16(_g0, Bst + (sel) * 16384 + cb0 * 1024);                           \
    GLOAD_LDS16(_g1, Bst + (sel) * 16384 + (cb0 + 1) * 1024);                     \
  }

  // stage GEMM1 kb=0 into buf0 now — lands during phase 1
  STAGE_B(Pb, 0, 0)

  // ---- phase 1: h1 = relu(u[j] + v[i] + bca) for j = 0..127 ----
  {
    int k2 = tid & 255;                                    // fixed col-pair
    float2 vv = *(const float2*)(v + (b * 128 + i) * 512 + 2 * k2);
    float2 bc = *(const float2*)(bca + 2 * k2);
    float vb0 = vv.x + bc.x, vb1 = vv.y + bc.y;
    const float* ub = u + (b * 128) * 512;
#pragma unroll 4
    for (int it = 0; it < 64; it++) {
      int r = it * 2 + (tid >> 8);                         // 0..127
      float2 uu = *(const float2*)(ub + r * 512 + 2 * k2);
      float x0 = fmaxf(uu.x + vb0, 0.f);
      float x1 = fmaxf(uu.y + vb1, 0.f);
      unsigned short s0 = __builtin_bit_cast(unsigned short, (__bf16)x0);
      unsigned short s1 = __builtin_bit_cast(unsigned short, (__bf16)x1);
      unsigned int pk = ((unsigned int)s1 << 16) | (unsigned int)s0;
      int rt = r & 63;
      int wbyte = ((r >> 6) << 16) + rt * 1024 + ((4 * k2) ^ ((rt & 15) << 4));
      *(unsigned int*)(h_raw + wbyte) = pk;
    }
  }
  __syncthreads();   // h ready + buf0 staged (implicit vmcnt(0) drain)

  f32x16 acc0[4], acc1[4];             // tile 0 / tile 1

  // ---- GEMM 1: h2 = h1 @ Wcb (B from LDS double-buffer) ----
#pragma unroll
  for (int nb = 0; nb < 4; nb++)
#pragma unroll
    for (int r = 0; r < 16; r++) { acc0[nb][r] = 0.f; acc1[nb][r] = 0.f; }
#pragma unroll 2
  for (int kb = 0; kb < 32; kb++) {
    int sel = kb & 1;
    if (kb < 31) STAGE_B(Pb, kb + 1, sel ^ 1)
    const char* bb = Bst + sel * 16384 + lane * 16;
    bf16x8 b0 = *(const bf16x8*)(bb + (cg4 + 0) * 1024);
    bf16x8 b1 = *(const bf16x8*)(bb + (cg4 + 1) * 1024);
    bf16x8 b2 = *(const bf16x8*)(bb + (cg4 + 2) * 1024);
    bf16x8 b3 = *(const bf16x8*)(bb + (cg4 + 3) * 1024);
    int abyte = arow * 1024 + (((kb * 16 + klo) * 2) ^ sA);
    bf16x8 a0 = *(const bf16x8*)(h_raw + abyte);
    bf16x8 a1 = *(const bf16x8*)(h_raw + 65536 + abyte);
    acc0[0] = __builtin_amdgcn_mfma_f32_32x32x16_bf16(a0, b0, acc0[0], 0, 0, 0);
    acc1[0] = __builtin_amdgcn_mfma_f32_32x32x16_bf16(a1, b0, acc1[0], 0, 0, 0);
    acc0[1] = __builtin_amdgcn_mfma_f32_32x32x16_bf16(a0, b1, acc0[1], 0, 0, 0);
    acc1[1] = __builtin_amdgcn_mfma_f32_32x32x16_bf16(a1, b1, acc1[1], 0, 0, 0);
    acc0[2] = __builtin_amdgcn_mfma_f32_32x32x16_bf16(a0, b2, acc0[2], 0, 0, 0);
    acc1[2] = __builtin_amdgcn_mfma_f32_32x32x16_bf16(a1, b2, acc1[2], 0, 0, 0);
    acc0[3] = __builtin_amdgcn_mfma_f32_32x32x16_bf16(a0, b3, acc0[3], 0, 0, 0);
    acc1[3] = __builtin_amdgcn_mfma_f32_32x32x16_bf16(a1, b3, acc1[3], 0, 0, 0);
    __syncthreads();               // buf[sel] reads done; buf[sel^1] staged
  }
  // cur parity back to 0; buf0's last readers were kb=30 (2 barriers ago)
  STAGE_B(Pc, 0, 0)                // lands during epilogue 1

  // ---- epilogue 1: h2 = relu(acc + bcb) -> bf16 LDS (swizzled), both tiles ----
#pragma unroll
  for (int nb = 0; nb < 4; nb++) {
    int cn = n0 + nb * 32 + (lane & 31);
    float bbv = bcb[cn];
#pragma unroll
    for (int r = 0; r < 16; r++) {
      int row = mrow + (r & 3) + 8 * (r >> 2) + 4 * (lane >> 5);
      int byte_ = row * 1024 + ((cn * 2) ^ ((row & 15) << 4));
      *(__bf16*)(h_raw + byte_) = (__bf16)fmaxf(acc0[nb][r] + bbv, 0.f);
      *(__bf16*)(h_raw + 65536 + byte_) = (__bf16)fmaxf(acc1[nb][r] + bbv, 0.f);
    }
  }
  __syncthreads();                 // h2 ready + Pc buf0 staged

  // ---- GEMM 2: h3 = h2 @ Wcc (B from LDS double-buffer) ----
#pragma unroll
  for (int nb = 0; nb < 4; nb++)
#pragma unroll
    for (int r = 0; r < 16; r++) { acc0[nb][r] = 0.f; acc1[nb][r] = 0.f; }
#pragma unroll 2
  for (int kb = 0; kb < 32; kb++) {
    int sel = kb & 1;
    if (kb < 31) STAGE_B(Pc, kb + 1, sel ^ 1)
    const char* bb = Bst + sel * 16384 + lane * 16;
    bf16x8 b0 = *(const bf16x8*)(bb + (cg4 + 0) * 1024);
    bf16x8 b1 = *(const bf16x8*)(bb + (cg4 + 1) * 1024);
    bf16x8 b2 = *(const bf16x8*)(bb + (cg4 + 2) * 1024);
    bf16x8 b3 = *(const bf16x8*)(bb + (cg4 + 3) * 1024);
    int abyte = arow * 1024 + (((kb * 16 + klo) * 2) ^ sA);
    bf16x8 a0 = *(const bf16x8*)(h_raw + abyte);
    bf16x8 a1 = *(const bf16x8*)(h_raw + 65536 + abyte);
    acc0[0] = __builtin_amdgcn_mfma_f32_32x32x16_bf16(a0, b0, acc0[0], 0, 0, 0);
    acc1[0] = __builtin_amdgcn_mfma_f32_32x32x16_bf16(a1, b0, acc1[0], 0, 0, 0);
    acc0[1] = __builtin_amdgcn_mfma_f32_32x32x16_bf16(a0, b1, acc0[1], 0, 0, 0);
    acc1[1] = __builtin_amdgcn_mfma_f32_32x32x16_bf16(a1, b1, acc1[1], 0, 0, 0);
    acc0[2] = __builtin_amdgcn_mfma_f32_32x32x16_bf16(a0, b2, acc0[2], 0, 0, 0);
    acc1[2] = __builtin_amdgcn_mfma_f32_32x32x16_bf16(a1, b2, acc1[2], 0, 0, 0);
    acc0[3] = __builtin_amdgcn_mfma_f32_32x32x16_bf16(a0, b3, acc0[3], 0, 0, 0);
    acc1[3] = __builtin_amdgcn_mfma_f32_32x32x16_bf16(a1, b3, acc1[3], 0, 0, 0);
    __syncthreads();
  }

  // ---- epilogue 2: h3 = relu(acc + bcc); fold Wo; shfl-reduce (fp32) ----
  float p0[16][2] = {}, p1[16][2] = {};
#pragma unroll
  for (int nb = 0; nb < 4; nb++) {
    int cn = n0 + nb * 32 + (lane & 31);
    float bcv = bcc[cn];
    float2 wov = *(const float2*)(Wo + cn * 2);
#pragma unroll
    for (int r = 0; r < 16; r++) {
      float h30 = fmaxf(acc0[nb][r] + bcv, 0.f);
      float h31 = fmaxf(acc1[nb][r] + bcv, 0.f);
      p0[r][0] += h30 * wov.x; p0[r][1] += h30 * wov.y;
      p1[r][0] += h31 * wov.x; p1[r][1] += h31 * wov.y;
    }
  }
#pragma unroll
  for (int m = 1; m <= 16; m <<= 1) {
#pragma unroll
    for (int r = 0; r < 16; r++) {
      p0[r][0] += __shfl_xor(p0[r][0], m, 64);
      p0[r][1] += __shfl_xor(p0[r][1], m, 64);
      p1[r][0] += __shfl_xor(p1[r][0], m, 64);
      p1[r][1] += __shfl_xor(p1[r][1], m, 64);
    }
  }
  __syncthreads();                 // all GEMM2 LDS reads done; reuse h_raw
  float* red = (float*)h_raw;      // [4 colgroups][128 rows][2] = 4 KB
  if ((lane & 31) == 0) {
    int hh = lane >> 5, cg = w >> 1;
#pragma unroll
    for (int r = 0; r < 16; r++) {
      int row = mrow + (r & 3) + 8 * (r >> 2) + 4 * hh;
      red[(cg * 128 + row) * 2 + 0] = p0[r][0];
      red[(cg * 128 + row) * 2 + 1] = p0[r][1];
      red[(cg * 128 + 64 + row) * 2 + 0] = p1[r][0];
      red[(cg * 128 + 64 + row) * 2 + 1] = p1[r][1];
    }
  }
  __syncthreads();
  if (tid < 256) {
    int row = tid >> 1, d = tid & 1;
    float s = red[(0 * 128 + row) * 2 + d] + red[(1 * 128 + row) * 2 + d] +
              red[(2 * 128 + row) * 2 + d] + red[(3 * 128 + row) * 2 + d] + bo[d];
    out[((b * 128 + i) * 128 + row) * 2 + d] = s;
  }
#undef STAGE_B
}

// ---------------------------------------------------------------------------
extern "C" void kernel_launch(void* const* d_in, const int* in_sizes, int n_in,
                              void* d_out, int out_size, void* d_ws, size_t ws_size,
                              hipStream_t stream) {
  const float* x   = (const float*)d_in[0];
  const float* Wa  = (const float*)d_in[1];
  const float* ba  = (const float*)d_in[2];
  const float* Wb  = (const float*)d_in[3];
  const float* bb  = (const float*)d_in[4];
  const float* Wca = (const float*)d_in[5];
  const float* bca = (const float*)d_in[6];
  const float* Wcb = (const float*)d_in[7];
  const float* bcb = (const float*)d_in[8];
  const float* Wcc = (const float*)d_in[9];
  const float* bcc = (const float*)d_in[10];
  const float* Wo  = (const float*)d_in[11];
  const float* bo  = (const float*)d_in[12];
  float* out = (float*)d_out;

  char* ws = (char*)d_ws;
  float* f1 = (float*)(ws);                          // 2 MB
  float* f  = (float*)(ws + (2u << 20));             // 2 MB
  float* u  = (float*)(ws + (4u << 20));             // 2 MB
  float* v  = (float*)(ws + (6u << 20));             // 2 MB
  __bf16* Pb = (__bf16*)(ws + (8u << 20));           // 512 KB packed Wcb
  __bf16* Pc = (__bf16*)(ws + (8u << 20) + (512u << 10));  // 512 KB packed Wcc

  prep_pack<<<2048, 256, 0, stream>>>(Wcb, Wcc, Pb, Pc);
  gemm_f32<<<dim3(16, 16), 256, 0, stream>>>(x, Wa, ba, f1, 256, 512, 1);
  gemm_f32<<<dim3(16, 16), 256, 0, stream>>>(f1, Wb, bb, f, 512, 512, 1);
  gemm_uv<<<dim3(16, 32), 256, 0, stream>>>(f, Wca, u, v);
  edge_kernel<<<1024, 512, 0, stream>>>(u, v, (const bf16x8*)Pb, (const bf16x8*)Pc,
                                        bca, bcb, bcc, Wo, bo, out);
}